// Round 15
// baseline (41.102 us; speedup 1.0000x reference)
//
#include <hip/hip_runtime.h>
#include <stdint.h>

// shape (1,1,192,224,192) f32
#define DD 192
#define HH 224
#define WW 192
#define PLANE (HH*WW)          // 43008
#define TOTAL (DD*HH*WW)       // 8257536

#define HT 4                   // output rows per block (= 4 waves, 1 row each)
#define TROWS 6                // HT+2 halo rows staged
#define DSEG 6                 // d-outputs per block
#define NSEG (DD/DSEG)         // 32
#define HTILES (HH/HT)         // 56 (exact)
#define NT 256                 // 4 waves; lane = 3 w-positions (64*3 = 192)
#define NBLOCKS (HTILES*NSEG)  // 1792 = 7 blocks/CU exactly -> whole grid resident

#define TILEF (TROWS*WW)       // 1152 floats per input per plane-tile
#define BUFF (2*TILEF)         // 2304 floats per buffer (I then J)
#define NPIECE 576             // 16B pieces per plane-pair (12 rows x 48)
#define GUARD 4                // 16B head guard so lane0's [3l-1] read is in-bounds

typedef __attribute__((address_space(3))) uint32_t lds_t;
typedef __attribute__((address_space(1))) const uint32_t glb_t;

// Raw barrier + counted vmcnt. Per-wave ledger: wave 0 issues 3 loads/stage,
// waves 1-3 issue 2; each wave's WAIT retires exactly its oldest stage.
// WIDTH-16 ONLY: width-12 global_load_lds corrupts data on gfx950
// (R8/R13/R14 all nonzero absmax; every width-16 round exact).
#define BARRIER() asm volatile("s_barrier" ::: "memory")
#define WAITV3()  asm volatile("s_waitcnt vmcnt(3)" ::: "memory")
#define WAITV2()  asm volatile("s_waitcnt vmcnt(2)" ::: "memory")
#define WAITV0()  asm volatile("s_waitcnt vmcnt(0)" ::: "memory")
#define WAITS()   do { if (w0wave) { WAITV3(); } else { WAITV2(); } } while (0)

struct PP {  // per-plane aggregates for I and J (3 w-outputs each)
    float IPT[3], IPS[3], IHD[3];
    float JPT[3], JPS[3], JHD[3];
};

__global__ __launch_bounds__(NT) void ngf_main_kernel(
    const float* __restrict__ I, const float* __restrict__ J,
    float* __restrict__ partial)
{
    // All combine reads are b32 at (3*lane + c): 3 coprime 32 -> 2 lanes/bank
    // = conflict-free (rows are wave-uniform; row stride 192 = 0 mod 32).
    __shared__ __align__(16) float lds[GUARD + 2 * BUFF + 4];
    const float EPS2 = 0.04f;  // (2*0.1)^2 — 0.5 Sobel factor folded out

    int t    = threadIdx.x;
    int lane = t & 63;
    int w    = t >> 6;          // wave 0..3 = output h-row
    bool w0wave = (t < 64);     // wave-uniform
    int bid  = blockIdx.x;
    int th   = bid % HTILES;
    int seg  = bid / HTILES;
    int ds   = seg * DSEG;
    int hb   = th * HT;

    // --- staging: 576 float4 pieces, piece-contiguous LDS layout.
    //     piece p = inp*288 + r*48 + c  ->  LDS float offset 4p
    //     == inp*TILEF + r*WW + 4c (row-major), so combine addressing holds.
    //     Threads stage pieces {t, t+256} and wave 0 additionally {t+512}.
    const float* sp[3];
    int lo[3];
    #pragma unroll
    for (int m = 0; m < 3; ++m) {
        int p = t + m * NT;
        if (p >= NPIECE) p = 0;            // dummy for lanes without a 3rd piece
        int inp = (p >= NPIECE / 2) ? 1 : 0;
        int q   = p - inp * (NPIECE / 2);
        int r   = q / 48, c = q % 48;
        int srow = min(max(hb - 1 + r, 0), HH - 1);   // replicate h-halo at load
        sp[m] = (inp ? J : I) + srow * WW + c * 4;
        lo[m] = GUARD + 4 * p;
    }

    auto stage = [&](int dp, int buf) {
        size_t poff = (size_t)dp * PLANE;
        __builtin_amdgcn_global_load_lds((glb_t*)(sp[0] + poff),
            (lds_t*)(&lds[buf * BUFF + lo[0]]), 16, 0, 0);
        __builtin_amdgcn_global_load_lds((glb_t*)(sp[1] + poff),
            (lds_t*)(&lds[buf * BUFF + lo[1]]), 16, 0, 0);
        if (w0wave)
            __builtin_amdgcn_global_load_lds((glb_t*)(sp[2] + poff),
                (lds_t*)(&lds[buf * BUFF + lo[2]]), 16, 0, 0);
    };

    // --- compute mapping: lane covers w-positions 3*lane .. 3*lane+2 ---
    int l3 = 3 * lane;
    bool b0  = (lane == 0);    // true image left boundary
    bool b63 = (lane == 63);   // true image right boundary

    auto combine = [&](int buf) -> PP {
        PP P;
        #pragma unroll
        for (int j = 0; j < 3; ++j) {
            P.IPT[j] = 0.f; P.IPS[j] = 0.f; P.IHD[j] = 0.f;
            P.JPT[j] = 0.f; P.JPS[j] = 0.f; P.JHD[j] = 0.f;
        }
        const float* base = &lds[GUARD + buf * BUFF];
        #pragma unroll
        for (int b = 0; b < 3; ++b) {
            const float* BI = base + (w + b) * WW;   // wave-uniform row
            const float* BJ = BI + TILEF;
            {
                float Lr = BI[l3 - 1];
                float x0 = BI[l3], x1 = BI[l3 + 1], x2 = BI[l3 + 2];
                float Rr = BI[l3 + 3];
                float L = b0  ? x0 : Lr;   // replicate pad at w=0
                float R = b63 ? x2 : Rr;   // replicate pad at w=191
                float s0 = L  + x0 + x1;
                float s1 = x0 + x1 + x2;
                float s2 = x1 + x2 + R;
                P.IPT[0] += x1 - L;
                P.IPT[1] += x2 - x0;
                P.IPT[2] += R  - x1;
                P.IPS[0] += s0; P.IPS[1] += s1; P.IPS[2] += s2;
                if (b == 0) { P.IHD[0] -= s0; P.IHD[1] -= s1; P.IHD[2] -= s2; }
                if (b == 2) { P.IHD[0] += s0; P.IHD[1] += s1; P.IHD[2] += s2; }
            }
            {
                float Lr = BJ[l3 - 1];
                float x0 = BJ[l3], x1 = BJ[l3 + 1], x2 = BJ[l3 + 2];
                float Rr = BJ[l3 + 3];
                float L = b0  ? x0 : Lr;
                float R = b63 ? x2 : Rr;
                float s0 = L  + x0 + x1;
                float s1 = x0 + x1 + x2;
                float s2 = x1 + x2 + R;
                P.JPT[0] += x1 - L;
                P.JPT[1] += x2 - x0;
                P.JPT[2] += R  - x1;
                P.JPS[0] += s0; P.JPS[1] += s1; P.JPS[2] += s2;
                if (b == 0) { P.JHD[0] -= s0; P.JHD[1] -= s1; P.JHD[2] -= s2; }
                if (b == 2) { P.JHD[0] += s0; P.JHD[1] += s1; P.JHD[2] += s2; }
            }
        }
        return P;
    };

    auto dcl = [&](int m) { return min(max(ds + m, 0), DD - 1); };

    // --- prologue ---
    // plane m -> buffer (m+1)&1 :  -1->0, 0->1, 1->0, 2->1
    PP p[3];
    stage(dcl(-1), 0);           // outstanding: {S-1}
    stage(dcl(0), 1);            // {S-1, S0}
    WAITS(); BARRIER();          // plane -1 landed everywhere
    p[0] = combine(0);
    BARRIER();                   // all waves done reading buf0
    stage(dcl(1), 0);            // {S0, S1}
    WAITS(); BARRIER();          // plane 0 landed
    p[1] = combine(1);
    BARRIER();                   // done reading buf1
    stage(dcl(2), 1);            // {S1, S2}

    float acc = 0.0f;
    #pragma unroll
    for (int k = 0; k < DSEG; ++k) {
        int buf = k & 1;                 // plane k+1 sits in buffer (k+2)&1 = k&1
        if (k < DSEG - 1) { WAITS(); }   // retire S(k+1), keep S(k+2) in flight
        else             { WAITV0(); }   // last: drain
        BARRIER();                       // plane k+1 visible to all waves
        int sa = k % 3, sb2 = (k + 1) % 3, sc = (k + 2) % 3;
        p[sc] = combine(buf);

        #pragma unroll
        for (int j = 0; j < 3; ++j) {
            float Ix = p[sa].IPT[j] + p[sb2].IPT[j] + p[sc].IPT[j];
            float Iy = p[sa].IHD[j] + p[sb2].IHD[j] + p[sc].IHD[j];
            float Iz = p[sc].IPS[j] - p[sa].IPS[j];
            float Jx = p[sa].JPT[j] + p[sb2].JPT[j] + p[sc].JPT[j];
            float Jy = p[sa].JHD[j] + p[sb2].JHD[j] + p[sc].JHD[j];
            float Jz = p[sc].JPS[j] - p[sa].JPS[j];

            float Imag = fmaf(Ix, Ix, fmaf(Iy, Iy, fmaf(Iz, Iz, EPS2)));
            float Jmag = fmaf(Jx, Jx, fmaf(Jy, Jy, fmaf(Jz, Jz, EPS2)));
            float dot  = fmaf(Ix, Jx, fmaf(Iy, Jy, Iz * Jz));
            acc += 1.0f - (dot * dot) * __builtin_amdgcn_rcpf(Imag * Jmag);
        }

        if (k < DSEG - 1) {
            BARRIER();                   // all waves done reading buf
            if (k <= DSEG - 3)
                stage(dcl(k + 3), buf);  // plane k+3 -> buffer (k+4)&1 = k&1 ✓
        }
    }

    // --- reduction: 4 waves ---
    #pragma unroll
    for (int o = 32; o > 0; o >>= 1)
        acc += __shfl_down(acc, o, 64);

    __shared__ float smem[NT / 64];
    if (lane == 0) smem[w] = acc;
    __syncthreads();
    if (t == 0)
        partial[bid] = smem[0] + smem[1] + smem[2] + smem[3];
}

__global__ __launch_bounds__(256) void ngf_reduce_kernel(
    const float* __restrict__ partial, float* __restrict__ out)
{
    double acc = 0.0;
    for (int i = threadIdx.x; i < NBLOCKS; i += blockDim.x)
        acc += (double)partial[i];

    #pragma unroll
    for (int o = 32; o > 0; o >>= 1)
        acc += __shfl_down(acc, o, 64);

    __shared__ double smem[4];
    int lane = threadIdx.x & 63;
    int wid  = threadIdx.x >> 6;
    if (lane == 0) smem[wid] = acc;
    __syncthreads();
    if (threadIdx.x == 0) {
        double s = smem[0] + smem[1] + smem[2] + smem[3];
        out[0] = (float)(s / (double)TOTAL);
    }
}

extern "C" void kernel_launch(void* const* d_in, const int* in_sizes, int n_in,
                              void* d_out, int out_size, void* d_ws, size_t ws_size,
                              hipStream_t stream)
{
    const float* I = (const float*)d_in[0];
    const float* J = (const float*)d_in[1];
    float* out = (float*)d_out;
    float* partial = (float*)d_ws;   // NBLOCKS floats

    ngf_main_kernel<<<NBLOCKS, NT, 0, stream>>>(I, J, partial);
    ngf_reduce_kernel<<<1, 256, 0, stream>>>(partial, out);
}

// Round 16
// 30.248 us; speedup vs baseline: 1.3588x; 1.3588x over previous
//
#include <hip/hip_runtime.h>
#include <stdint.h>

// shape (1,1,192,224,192) f32
#define DD 192
#define HH 224
#define WW 192
#define PLANE (HH*WW)          // 43008
#define TOTAL (DD*HH*WW)       // 8257536

#define HT 4                   // output rows per block (= 4 waves, 1 row each)
#define TROWS 6                // HT+2 halo rows staged
#define DSEG 6                 // d-outputs per block
#define NSEG (DD/DSEG)         // 32
#define HTILES (HH/HT)         // 56 (exact)
#define NT 256                 // 4 waves; lane = 3 w-positions (64*3 = 192)
#define NBLOCKS (HTILES*NSEG)  // 1792 = 7 blocks/CU exactly -> whole grid resident

#define TILEF (TROWS*WW)       // 1152 floats per input per plane-tile
#define BUFF (2*TILEF)         // 2304 floats per buffer (I then J)
#define NPIECE 576             // 16B pieces per plane-pair (12 rows x 48)
#define GUARD 4                // 16B head guard so lane0's [3l-1] read is in-bounds

typedef __attribute__((address_space(3))) uint32_t lds_t;
typedef __attribute__((address_space(1))) const uint32_t glb_t;

// Raw barrier + counted vmcnt. UNIFORM ledger: every wave issues exactly 3
// width-16 loads per stage (load 2 is the same 64-piece wave-load duplicated
// by all 4 waves -- benign same-data LDS writes, L2-hit duplicates), so
// WAITV3 retires exactly the oldest stage for every wave, no branches.
// WIDTH-16 ONLY: width-12 global_load_lds corrupts data on gfx950
// (R8/R13/R14 nonzero absmax; every width-16 round exact).
#define BARRIER() asm volatile("s_barrier" ::: "memory")
#define WAITV3()  asm volatile("s_waitcnt vmcnt(3)" ::: "memory")
#define WAITV0()  asm volatile("s_waitcnt vmcnt(0)" ::: "memory")

struct PP {  // per-plane aggregates for I and J (3 w-outputs each)
    float IPT[3], IPS[3], IHD[3];
    float JPT[3], JPS[3], JHD[3];
};

__global__ __launch_bounds__(NT) void ngf_main_kernel(
    const float* __restrict__ I, const float* __restrict__ J,
    float* __restrict__ partial)
{
    // All combine reads are b32 at (3*lane + c): 3 coprime 32 -> 2 lanes/bank
    // = conflict-free (rows are wave-uniform; row stride 192 = 0 mod 32).
    __shared__ __align__(16) float lds[GUARD + 2 * BUFF + 4];
    const float EPS2 = 0.04f;  // (2*0.1)^2 — 0.5 Sobel factor folded out

    int t    = threadIdx.x;
    int lane = t & 63;
    int w    = t >> 6;          // wave 0..3 = output h-row
    int bid  = blockIdx.x;
    int th   = bid % HTILES;
    int seg  = bid / HTILES;
    int ds   = seg * DSEG;
    int hb   = th * HT;

    // --- staging: 576 float4 pieces, piece-contiguous LDS layout.
    //     piece p = inp*288 + r*48 + c  ->  LDS float offset 4p
    //     == inp*TILEF + r*WW + 4c (row-major), so combine addressing holds.
    //     Loads 0,1: p = t, t+256 (uniform). Load 2: p = 512+lane for ALL
    //     waves (4x duplicate of the same data -> benign, uniform vmcnt).
    const float* sp[3];
    int lo[3];
    #pragma unroll
    for (int m = 0; m < 3; ++m) {
        int p = (m < 2) ? (t + m * NT) : (512 + lane);
        int inp = (p >= NPIECE / 2) ? 1 : 0;
        int q   = p - inp * (NPIECE / 2);
        int r   = q / 48, c = q % 48;
        int srow = min(max(hb - 1 + r, 0), HH - 1);   // replicate h-halo at load
        sp[m] = (inp ? J : I) + srow * WW + c * 4;
        lo[m] = GUARD + 4 * p;
    }

    auto stage = [&](int dp, int buf) {
        size_t poff = (size_t)dp * PLANE;
        #pragma unroll
        for (int m = 0; m < 3; ++m) {
            __builtin_amdgcn_global_load_lds((glb_t*)(sp[m] + poff),
                (lds_t*)(&lds[buf * BUFF + lo[m]]), 16, 0, 0);
        }
    };

    // --- compute mapping: lane covers w-positions 3*lane .. 3*lane+2 ---
    int l3 = 3 * lane;
    bool b0  = (lane == 0);    // true image left boundary
    bool b63 = (lane == 63);   // true image right boundary

    auto combine = [&](int buf) -> PP {
        PP P;
        #pragma unroll
        for (int j = 0; j < 3; ++j) {
            P.IPT[j] = 0.f; P.IPS[j] = 0.f; P.IHD[j] = 0.f;
            P.JPT[j] = 0.f; P.JPS[j] = 0.f; P.JHD[j] = 0.f;
        }
        const float* base = &lds[GUARD + buf * BUFF];
        #pragma unroll
        for (int b = 0; b < 3; ++b) {
            const float* BI = base + (w + b) * WW;   // wave-uniform row
            const float* BJ = BI + TILEF;
            {
                float Lr = BI[l3 - 1];
                float x0 = BI[l3], x1 = BI[l3 + 1], x2 = BI[l3 + 2];
                float Rr = BI[l3 + 3];
                float L = b0  ? x0 : Lr;   // replicate pad at w=0
                float R = b63 ? x2 : Rr;   // replicate pad at w=191
                float s0 = L  + x0 + x1;
                float s1 = x0 + x1 + x2;
                float s2 = x1 + x2 + R;
                P.IPT[0] += x1 - L;
                P.IPT[1] += x2 - x0;
                P.IPT[2] += R  - x1;
                P.IPS[0] += s0; P.IPS[1] += s1; P.IPS[2] += s2;
                if (b == 0) { P.IHD[0] -= s0; P.IHD[1] -= s1; P.IHD[2] -= s2; }
                if (b == 2) { P.IHD[0] += s0; P.IHD[1] += s1; P.IHD[2] += s2; }
            }
            {
                float Lr = BJ[l3 - 1];
                float x0 = BJ[l3], x1 = BJ[l3 + 1], x2 = BJ[l3 + 2];
                float Rr = BJ[l3 + 3];
                float L = b0  ? x0 : Lr;
                float R = b63 ? x2 : Rr;
                float s0 = L  + x0 + x1;
                float s1 = x0 + x1 + x2;
                float s2 = x1 + x2 + R;
                P.JPT[0] += x1 - L;
                P.JPT[1] += x2 - x0;
                P.JPT[2] += R  - x1;
                P.JPS[0] += s0; P.JPS[1] += s1; P.JPS[2] += s2;
                if (b == 0) { P.JHD[0] -= s0; P.JHD[1] -= s1; P.JHD[2] -= s2; }
                if (b == 2) { P.JHD[0] += s0; P.JHD[1] += s1; P.JHD[2] += s2; }
            }
        }
        return P;
    };

    auto dcl = [&](int m) { return min(max(ds + m, 0), DD - 1); };

    // --- prologue ---
    // plane m -> buffer (m+1)&1 :  -1->0, 0->1, 1->0, 2->1
    PP p[3];
    stage(dcl(-1), 0);           // outstanding: {S-1}
    stage(dcl(0), 1);            // {S-1, S0}
    WAITV3(); BARRIER();         // plane -1 landed everywhere
    p[0] = combine(0);
    BARRIER();                   // all waves done reading buf0
    stage(dcl(1), 0);            // {S0, S1}
    WAITV3(); BARRIER();         // plane 0 landed
    p[1] = combine(1);
    BARRIER();                   // done reading buf1
    stage(dcl(2), 1);            // {S1, S2}

    float acc = 0.0f;
    #pragma unroll
    for (int k = 0; k < DSEG; ++k) {
        int buf = k & 1;                 // plane k+1 sits in buffer (k+2)&1 = k&1
        if (k < DSEG - 1) { WAITV3(); }  // retire S(k+1), keep S(k+2) in flight
        else             { WAITV0(); }   // last: drain
        BARRIER();                       // plane k+1 visible to all waves
        int sa = k % 3, sb2 = (k + 1) % 3, sc = (k + 2) % 3;
        p[sc] = combine(buf);

        #pragma unroll
        for (int j = 0; j < 3; ++j) {
            float Ix = p[sa].IPT[j] + p[sb2].IPT[j] + p[sc].IPT[j];
            float Iy = p[sa].IHD[j] + p[sb2].IHD[j] + p[sc].IHD[j];
            float Iz = p[sc].IPS[j] - p[sa].IPS[j];
            float Jx = p[sa].JPT[j] + p[sb2].JPT[j] + p[sc].JPT[j];
            float Jy = p[sa].JHD[j] + p[sb2].JHD[j] + p[sc].JHD[j];
            float Jz = p[sc].JPS[j] - p[sa].JPS[j];

            float Imag = fmaf(Ix, Ix, fmaf(Iy, Iy, fmaf(Iz, Iz, EPS2)));
            float Jmag = fmaf(Jx, Jx, fmaf(Jy, Jy, fmaf(Jz, Jz, EPS2)));
            float dot  = fmaf(Ix, Jx, fmaf(Iy, Jy, Iz * Jz));
            acc += 1.0f - (dot * dot) * __builtin_amdgcn_rcpf(Imag * Jmag);
        }

        if (k < DSEG - 1) {
            BARRIER();                   // all waves done reading buf
            if (k <= DSEG - 3)
                stage(dcl(k + 3), buf);  // plane k+3 -> buffer (k+4)&1 = k&1 ✓
        }
    }

    // --- reduction: 4 waves ---
    #pragma unroll
    for (int o = 32; o > 0; o >>= 1)
        acc += __shfl_down(acc, o, 64);

    __shared__ float smem[NT / 64];
    if (lane == 0) smem[w] = acc;
    __syncthreads();
    if (t == 0)
        partial[bid] = smem[0] + smem[1] + smem[2] + smem[3];
}

__global__ __launch_bounds__(256) void ngf_reduce_kernel(
    const float* __restrict__ partial, float* __restrict__ out)
{
    double acc = 0.0;
    for (int i = threadIdx.x; i < NBLOCKS; i += blockDim.x)
        acc += (double)partial[i];

    #pragma unroll
    for (int o = 32; o > 0; o >>= 1)
        acc += __shfl_down(acc, o, 64);

    __shared__ double smem[4];
    int lane = threadIdx.x & 63;
    int wid  = threadIdx.x >> 6;
    if (lane == 0) smem[wid] = acc;
    __syncthreads();
    if (threadIdx.x == 0) {
        double s = smem[0] + smem[1] + smem[2] + smem[3];
        out[0] = (float)(s / (double)TOTAL);
    }
}

extern "C" void kernel_launch(void* const* d_in, const int* in_sizes, int n_in,
                              void* d_out, int out_size, void* d_ws, size_t ws_size,
                              hipStream_t stream)
{
    const float* I = (const float*)d_in[0];
    const float* J = (const float*)d_in[1];
    float* out = (float*)d_out;
    float* partial = (float*)d_ws;   // NBLOCKS floats

    ngf_main_kernel<<<NBLOCKS, NT, 0, stream>>>(I, J, partial);
    ngf_reduce_kernel<<<1, 256, 0, stream>>>(partial, out);
}